// Round 1
// baseline (34753.339 us; speedup 1.0000x reference)
//
#include <hip/hip_runtime.h>
#include <hip/hip_cooperative_groups.h>

namespace cg = cooperative_groups;

// Problem constants
#define BB 64
#define TT 1024
#define DD 768
#define NN 768
#define NWG 192      // workgroups; each owns NCH h-columns for all 64 batch rows
#define NCH 4        // h-columns per WG -> 16 gate columns (4 gates x 4)
#define NKB 48       // combined K = 1536 = 48 blocks of 32

typedef _Float16 f16x8 __attribute__((ext_vector_type(8)));
typedef float f32x4 __attribute__((ext_vector_type(4)));

__device__ __forceinline__ float hsig(float v) {
    return fminf(fmaxf(0.2f * v + 0.5f, 0.0f), 1.0f);
}

// Persistent cooperative PLSTM kernel.
// Combined K layout: k in [0,768) = recurrent (h @ Wr), k in [768,1536) = input (x @ Wk).
// Gate-column order within a WG: c = gate*4 + colh, gates {0:i, 1:f, 2:c~, 3:o}.
__global__ __launch_bounds__(256, 1) void plstm_kernel(
    const float* __restrict__ x, const float* __restrict__ h0,
    const float* __restrict__ c0,
    const float* __restrict__ Wki, const float* __restrict__ Wri,
    const float* __restrict__ Wkf, const float* __restrict__ Wrf,
    const float* __restrict__ Wkc, const float* __restrict__ Wrc,
    const float* __restrict__ Wko, const float* __restrict__ Wro,
    float* __restrict__ out, _Float16* __restrict__ hbuf)
{
    // Weights in MFMA-B fragment order: element (kb, lane, j) =
    //   Wcomb[k = kb*32 + (lane>>4)*8 + j][c = lane&15]
    // -> inner-loop read is lane-contiguous 16B (stride-1 ds_read_b128, conflict-free)
    __shared__ _Float16 Wf[NKB * 64 * 8];     // 49152 B
    __shared__ float gbuf[BB][17];            // gate pre-activations, padded pitch
    __shared__ float cst[BB][NCH];            // c state for this WG's columns

    const int tid = threadIdx.x;
    const int wg  = blockIdx.x;
    const int n0  = wg * NCH;

    const float* Wr[4] = {Wri, Wrf, Wrc, Wro};
    const float* Wk[4] = {Wki, Wkf, Wkc, Wko};

    // ---- one-time prologue: stage fp16 weight fragments ----
    for (int kb = 0; kb < NKB; ++kb) {
        for (int e = tid; e < 512; e += 256) {
            int lane_ = e >> 3, j = e & 7;
            int k = kb * 32 + (lane_ >> 4) * 8 + j;
            int c = lane_ & 15;
            int g = c >> 2;
            int ng = n0 + (c & 3);
            float v = (k < NN) ? Wr[g][k * NN + ng] : Wk[g][(k - NN) * NN + ng];
            Wf[(kb * 64 + lane_) * 8 + j] = (_Float16)v;
        }
    }
    {
        int b = tid >> 2, ch = tid & 3;
        cst[b][ch] = c0[b * NN + n0 + ch];
        hbuf[b * NN + n0 + ch] = (_Float16)h0[b * NN + n0 + ch];
    }
    cg::this_grid().sync();

    const int w    = tid >> 6;     // wave id 0..3 -> owns batch rows [w*16, w*16+16)
    const int lane = tid & 63;
    const int q    = lane >> 4;    // k-quad within MFMA
    const int nl   = lane & 15;    // local gate column / A row-in-tile
    const int m    = w * 16 + nl;  // global batch row for A fragments

    const _Float16* wfrag = &Wf[lane * 8];                       // +512 elems per kb
    const float*    xbase = x + (size_t)m * (TT * DD) + q * 8;   // x[m][.][q*8..]
    float*          outcol = out + (size_t)n0;

    for (int t = 0; t < TT; ++t) {
        const _Float16* hr = hbuf + (t & 1) * (BB * NN) + m * NN + q * 8;
        _Float16*       hw = hbuf + ((t + 1) & 1) * (BB * NN);
        f32x4 acc = {0.f, 0.f, 0.f, 0.f};

        // Recurrent half: A = h_{t-1} (fp16 double buffer in ws)
        #pragma unroll 8
        for (int kb = 0; kb < 24; ++kb) {
            f16x8 a  = *(const f16x8*)(hr + kb * 32);
            f16x8 bf = *(const f16x8*)(wfrag + kb * 512);
            acc = __builtin_amdgcn_mfma_f32_16x16x32_f16(a, bf, acc, 0, 0, 0);
        }
        // Input half: A = x[:,t,:] (fp32 -> fp16 on the fly)
        const float* xp = xbase + t * DD;
        #pragma unroll 4
        for (int kb = 0; kb < 24; ++kb) {
            f32x4 x0 = *(const f32x4*)(xp + kb * 32);
            f32x4 x1 = *(const f32x4*)(xp + kb * 32 + 4);
            f16x8 a;
            a[0] = (_Float16)x0[0]; a[1] = (_Float16)x0[1];
            a[2] = (_Float16)x0[2]; a[3] = (_Float16)x0[3];
            a[4] = (_Float16)x1[0]; a[5] = (_Float16)x1[1];
            a[6] = (_Float16)x1[2]; a[7] = (_Float16)x1[3];
            f16x8 bf = *(const f16x8*)(wfrag + (kb + 24) * 512);
            acc = __builtin_amdgcn_mfma_f32_16x16x32_f16(a, bf, acc, 0, 0, 0);
        }

        // D layout (measured): col = lane&15, row = (lane>>4)*4 + reg
        #pragma unroll
        for (int r = 0; r < 4; ++r)
            gbuf[w * 16 + q * 4 + r][nl] = acc[r];
        __syncthreads();

        // Pointwise gates: 256 threads = 64 batch x 4 h-cols
        {
            int b = tid >> 2, ch = tid & 3;
            float vi = gbuf[b][ch];
            float vf = gbuf[b][4 + ch];
            float vg = gbuf[b][8 + ch];
            float vo = gbuf[b][12 + ch];
            float fi = hsig(vi), ff = hsig(vf), fo = hsig(vo);
            float fg = tanhf(vg);
            float cn = cst[b][ch] * ff + fi * fg;
            cst[b][ch] = cn;
            float hn = tanhf(cn) * fo;
            outcol[(size_t)b * (TT * NN) + (size_t)t * NN + ch] = hn;
            hw[b * NN + n0 + ch] = (_Float16)hn;
        }
        cg::this_grid().sync();
    }
}

extern "C" void kernel_launch(void* const* d_in, const int* in_sizes, int n_in,
                              void* d_out, int out_size, void* d_ws, size_t ws_size,
                              hipStream_t stream) {
    const float* xp  = (const float*)d_in[0];
    const float* h0p = (const float*)d_in[1];
    const float* c0p = (const float*)d_in[2];
    const float* wki = (const float*)d_in[3];
    const float* wri = (const float*)d_in[4];
    const float* wkf = (const float*)d_in[5];
    const float* wrf = (const float*)d_in[6];
    const float* wkc = (const float*)d_in[7];
    const float* wrc = (const float*)d_in[8];
    const float* wko = (const float*)d_in[9];
    const float* wro = (const float*)d_in[10];
    float* outp = (float*)d_out;
    _Float16* hbufp = (_Float16*)d_ws;   // 2 * 64 * 768 fp16 = 196,608 B

    void* args[] = {(void*)&xp,  (void*)&h0p, (void*)&c0p,
                    (void*)&wki, (void*)&wri, (void*)&wkf, (void*)&wrf,
                    (void*)&wkc, (void*)&wrc, (void*)&wko, (void*)&wro,
                    (void*)&outp, (void*)&hbufp};

    hipLaunchCooperativeKernel((const void*)plstm_kernel, dim3(NWG), dim3(256),
                               args, 0, stream);
}

// Round 2
// 12295.728 us; speedup vs baseline: 2.8265x; 2.8265x over previous
//
#include <hip/hip_runtime.h>
#include <stdint.h>

#define Bb 64
#define Ttot 1024
#define Dd 768
#define Nn 768

#define NWG_G 96     // primary recurrence WGs (32 gate-cols each)
#define NWG_F 192    // fallback recurrence WGs (16 gate-cols each)

typedef _Float16 f16x8 __attribute__((ext_vector_type(8)));
typedef float f32x4 __attribute__((ext_vector_type(4)));
typedef float f32x2 __attribute__((ext_vector_type(2)));

// ws layout (bytes)
#define CTR_OFF   0u                                   // 1025 * 4 = 4100
#define HRING_OFF 4352u                                // 2 slots * 49152 f16 = 196608
#define CST_OFF   (4352u + 196608u)                    // 200960: 64*768 f32 = 196608
#define WBK_OFF   (200960u + 196608u)                  // 397568: 4718592
#define WBR_OFF   (397568u + 4718592u)                 // 5116160: 4718592
#define G_OFF     (5116160u + 4718592u)                // 9834752 (256-aligned)
#define HSLOT_ELEMS 49152u                             // 24*4*64*8 f16 per slot

__device__ __forceinline__ float hsig(float v) {
    return fminf(fmaxf(0.2f * v + 0.5f, 0.0f), 1.0f);
}

// h-ring element offset for h[b][n], fragment layout [kb][q][b][j]
__device__ __forceinline__ uint32_t h_off(int n, int b) {
    return (uint32_t)((((n >> 5) * 4 + ((n >> 3) & 3)) * 64 + b) * 8 + (n & 7));
}

__global__ __launch_bounds__(256) void zero_ctr(uint32_t* __restrict__ ctr) {
    for (int e = threadIdx.x; e < Ttot + 1; e += 256) ctr[e] = 0u;
}

// Stage Wk and Wr into fp16 MFMA-B fragment buffers.
// Combined col c = 4*n + g, g in {0:i,1:f,2:c~,3:o}.
// WB[ct][kb][lane][j] = W_g[k = kb*32 + (lane>>4)*8 + j][n], c = ct*16 + (lane&15)
__global__ __launch_bounds__(256) void prep_w(
    const float* __restrict__ Wki, const float* __restrict__ Wri,
    const float* __restrict__ Wkf, const float* __restrict__ Wrf,
    const float* __restrict__ Wkc, const float* __restrict__ Wrc,
    const float* __restrict__ Wko, const float* __restrict__ Wro,
    _Float16* __restrict__ WBk, _Float16* __restrict__ WBr)
{
    int gw   = blockIdx.x * 4 + (threadIdx.x >> 6);   // 0..4607 = 192 ct * 24 kb
    int lane = threadIdx.x & 63;
    int ct = gw / 24, kb = gw - ct * 24;
    int c = ct * 16 + (lane & 15);
    int q = lane >> 4;
    int n = c >> 2, g = c & 3;
    const float* Wk[4] = {Wki, Wkf, Wkc, Wko};
    const float* Wr[4] = {Wri, Wrf, Wrc, Wro};
    f16x8 vk, vr;
    #pragma unroll
    for (int j = 0; j < 8; ++j) {
        int k = kb * 32 + q * 8 + j;
        vk[j] = (_Float16)Wk[g][(size_t)k * Nn + n];
        vr[j] = (_Float16)Wr[g][(size_t)k * Nn + n];
    }
    size_t o = ((size_t)gw * 64 + lane) * 8;
    *(f16x8*)(WBk + o) = vk;
    *(f16x8*)(WBr + o) = vr;
}

// Phase 1: G[(t-t0)*64 + b][c] = x[b][t][:] @ Wk_comb[:][c], fp16 out.
// Tile 128 tokens x 256 cols; 4 waves, each 64 rows x 128 cols.
__global__ __launch_bounds__(256, 2) void gemm_g(
    const float* __restrict__ x, const _Float16* __restrict__ WBk,
    _Float16* __restrict__ G, int t0, int tpb)
{
    __shared__ _Float16 As[128 * 72];   // pitch 72 f16 (bank-rotating, b128-aligned)
    int tid = threadIdx.x;
    int b    = blockIdx.x / tpb;
    int tloc = (blockIdx.x - b * tpb) * 128;
    int nt   = blockIdx.y;
    int w = tid >> 6, lane = tid & 63, q = lane >> 4, nl = lane & 15;
    int rh = w >> 1, ch = w & 1;
    f32x4 acc[4][8] = {};

    const float* xbase = x + ((size_t)b * Ttot + t0 + tloc) * Dd;
    int srow = tid >> 1, shalf = tid & 1;
    const float* sld = xbase + (size_t)srow * Dd + shalf * 32;
    _Float16* sst = As + srow * 72 + shalf * 32;

    for (int kc = 0; kc < 12; ++kc) {
        #pragma unroll
        for (int i = 0; i < 4; ++i) {
            f32x4 a0 = *(const f32x4*)(sld + kc * 64 + i * 8);
            f32x4 a1 = *(const f32x4*)(sld + kc * 64 + i * 8 + 4);
            f16x8 h;
            h[0]=(_Float16)a0[0]; h[1]=(_Float16)a0[1]; h[2]=(_Float16)a0[2]; h[3]=(_Float16)a0[3];
            h[4]=(_Float16)a1[0]; h[5]=(_Float16)a1[1]; h[6]=(_Float16)a1[2]; h[7]=(_Float16)a1[3];
            *(f16x8*)(sst + i * 8) = h;
        }
        __syncthreads();
        #pragma unroll
        for (int kbl = 0; kbl < 2; ++kbl) {
            int kbg = kc * 2 + kbl;
            f16x8 af[4];
            #pragma unroll
            for (int rt = 0; rt < 4; ++rt)
                af[rt] = *(const f16x8*)(As + (rh * 64 + rt * 16 + nl) * 72 + kbl * 32 + q * 8);
            const _Float16* bp = WBk + (((size_t)(nt * 16 + ch * 8) * 24 + kbg) * 64 + lane) * 8;
            #pragma unroll
            for (int cti = 0; cti < 8; ++cti) {
                f16x8 bf = *(const f16x8*)(bp + (size_t)cti * 12288);
                #pragma unroll
                for (int rt = 0; rt < 4; ++rt)
                    acc[rt][cti] = __builtin_amdgcn_mfma_f32_16x16x32_f16(af[rt], bf, acc[rt][cti], 0, 0, 0);
            }
        }
        __syncthreads();
    }
    // D layout: col = lane&15, row = q*4 + r
    #pragma unroll
    for (int cti = 0; cti < 8; ++cti) {
        int c = nt * 256 + ch * 128 + cti * 16 + nl;
        #pragma unroll
        for (int rt = 0; rt < 4; ++rt)
            #pragma unroll
            for (int r = 0; r < 4; ++r) {
                int rl = rh * 64 + rt * 16 + q * 4 + r;
                size_t grow = (size_t)(tloc + rl) * 64 + b;
                __builtin_nontemporal_store((_Float16)acc[rt][cti][r], G + grow * 3072 + c);
            }
    }
}

// Phase 2: persistent recurrence, 96 WGs x 256 thr, Wr frags register-resident.
__global__ __launch_bounds__(256, 1) void recur_g(
    const _Float16* __restrict__ WBr, const _Float16* __restrict__ G,
    const float* __restrict__ h0, const float* __restrict__ c0,
    float* __restrict__ out, _Float16* __restrict__ hring,
    uint32_t* __restrict__ ctr, float* __restrict__ cstbuf,
    int t0, int t1, int first)
{
    __shared__ float gbuf[64][36];
    __shared__ float cst[64][8];
    int tid = threadIdx.x, wg = blockIdx.x;
    int wid = tid >> 6, lane = tid & 63, q = lane >> 4, nl16 = lane & 15;

    // Register-resident B fragments: 2 col-tiles x 24 kb = 192 VGPRs
    f16x8 breg[2][24];
    #pragma unroll
    for (int ct = 0; ct < 2; ++ct)
        #pragma unroll
        for (int kb = 0; kb < 24; ++kb)
            breg[ct][kb] = *(const f16x8*)(WBr + (((size_t)(2 * wg + ct) * 24 + kb) * 64 + lane) * 8);

    for (int e = tid; e < 512; e += 256) {
        int b = e >> 3, c8 = e & 7;
        cst[b][c8] = first ? c0[(size_t)b * Nn + wg * 8 + c8]
                           : cstbuf[(size_t)b * Nn + wg * 8 + c8];
    }

    int bpw = tid >> 2, np = tid & 3;       // pointwise: (batch, n-pair)
    int ng = wg * 8 + 2 * np;               // n for pair base (even)
    uint32_t hoff = h_off(ng, bpw);         // j even -> 4B aligned

    if (first) {
        union { _Float16 h[2]; uint32_t u; } pk;
        pk.h[0] = (_Float16)h0[(size_t)bpw * Nn + ng];
        pk.h[1] = (_Float16)h0[(size_t)bpw * Nn + ng + 1];
        __hip_atomic_store((uint32_t*)(hring + hoff), pk.u,
                           __ATOMIC_RELAXED, __HIP_MEMORY_SCOPE_AGENT);
        __syncthreads();
        if (tid == 0)
            __hip_atomic_fetch_add(ctr, 1u, __ATOMIC_RELEASE, __HIP_MEMORY_SCOPE_AGENT);
    }

    int m = wid * 16 + nl16;                // batch row for A fragments
    for (int t = t0; t < t1; ++t) {
        if (tid == 0) {
            while (__hip_atomic_load(ctr + t, __ATOMIC_RELAXED, __HIP_MEMORY_SCOPE_AGENT)
                   < (uint32_t)NWG_G) {}
            __threadfence();
        }
        __syncthreads();

        const _Float16* hs = hring + (size_t)(t & 1) * HSLOT_ELEMS;
        f32x4 acc0 = {0.f, 0.f, 0.f, 0.f}, acc1 = {0.f, 0.f, 0.f, 0.f};
        #pragma unroll
        for (int kb = 0; kb < 24; ++kb) {
            f16x8 a = *(const f16x8*)(hs + ((kb * 4 + q) * 64 + m) * 8);
            acc0 = __builtin_amdgcn_mfma_f32_16x16x32_f16(a, breg[0][kb], acc0, 0, 0, 0);
            acc1 = __builtin_amdgcn_mfma_f32_16x16x32_f16(a, breg[1][kb], acc1, 0, 0, 0);
        }
        #pragma unroll
        for (int r = 0; r < 4; ++r) {
            gbuf[wid * 16 + q * 4 + r][nl16]      = acc0[r];
            gbuf[wid * 16 + q * 4 + r][16 + nl16] = acc1[r];
        }
        __syncthreads();
        {
            f32x4 v0 = *(const f32x4*)&gbuf[bpw][8 * np];
            f32x4 v1 = *(const f32x4*)&gbuf[bpw][8 * np + 4];
            f16x8 gg = *(const f16x8*)(G + ((size_t)(t - t0) * 64 + bpw) * 3072 + wg * 32 + 8 * np);

            float i0 = hsig(v0[0] + (float)gg[0]);
            float f0 = hsig(v0[1] + (float)gg[1]);
            float g0 = tanhf(v0[2] + (float)gg[2]);
            float o0 = hsig(v0[3] + (float)gg[3]);
            float cn0 = cst[bpw][2 * np] * f0 + i0 * g0;
            cst[bpw][2 * np] = cn0;
            float hv0 = tanhf(cn0) * o0;

            float i1 = hsig(v1[0] + (float)gg[4]);
            float f1 = hsig(v1[1] + (float)gg[5]);
            float g1 = tanhf(v1[2] + (float)gg[6]);
            float o1 = hsig(v1[3] + (float)gg[7]);
            float cn1 = cst[bpw][2 * np + 1] * f1 + i1 * g1;
            cst[bpw][2 * np + 1] = cn1;
            float hv1 = tanhf(cn1) * o1;

            f32x2 hv = {hv0, hv1};
            __builtin_nontemporal_store(hv, (f32x2*)(out + ((size_t)bpw * Ttot + t) * Nn + ng));
            union { _Float16 h[2]; uint32_t u; } pk;
            pk.h[0] = (_Float16)hv0; pk.h[1] = (_Float16)hv1;
            __hip_atomic_store((uint32_t*)(hring + (size_t)((t + 1) & 1) * HSLOT_ELEMS + hoff),
                               pk.u, __ATOMIC_RELAXED, __HIP_MEMORY_SCOPE_AGENT);
        }
        __syncthreads();   // drains vmcnt per wave before arrival
        if (tid == 0)
            __hip_atomic_fetch_add(ctr + t + 1, 1u, __ATOMIC_RELEASE, __HIP_MEMORY_SCOPE_AGENT);
    }
    for (int e = tid; e < 512; e += 256) {
        int b = e >> 3, c8 = e & 7;
        cstbuf[(size_t)b * Nn + wg * 8 + c8] = cst[b][c8];
    }
}

// Fallback (small ws): no G precompute, K=1536 (h | x), 192 WGs x 16 cols.
__global__ __launch_bounds__(256, 1) void recur_nog(
    const float* __restrict__ Wki, const float* __restrict__ Wri,
    const float* __restrict__ Wkf, const float* __restrict__ Wrf,
    const float* __restrict__ Wkc, const float* __restrict__ Wrc,
    const float* __restrict__ Wko, const float* __restrict__ Wro,
    const float* __restrict__ x, const float* __restrict__ h0,
    const float* __restrict__ c0, float* __restrict__ out,
    _Float16* __restrict__ hring, uint32_t* __restrict__ ctr)
{
    __shared__ float gbuf[64][20];
    __shared__ float cst[64][4];
    int tid = threadIdx.x, wg = blockIdx.x;
    int wid = tid >> 6, lane = tid & 63, q = lane >> 4, nl16 = lane & 15;
    const float* Wk[4] = {Wki, Wkf, Wkc, Wko};
    const float* Wr[4] = {Wri, Wrf, Wrc, Wro};

    int c = wg * 16 + nl16;
    int n = c >> 2, g = c & 3;
    f16x8 breg[48];
    #pragma unroll
    for (int kb = 0; kb < 48; ++kb)
        #pragma unroll
        for (int j = 0; j < 8; ++j) {
            int kk = (kb < 24 ? kb : kb - 24) * 32 + q * 8 + j;
            breg[kb][j] = (_Float16)((kb < 24 ? Wr[g] : Wk[g])[(size_t)kk * Nn + n]);
        }

    { int b = tid >> 2, c4 = tid & 3; cst[b][c4] = c0[(size_t)b * Nn + wg * 4 + c4]; }

    int bpw = tid >> 2, nl = tid & 3;
    int ngf = wg * 4 + nl;
    uint32_t hoff = h_off(ngf, bpw);        // 2B granularity (j may be odd)
    {
        union { _Float16 h; unsigned short u; } pk;
        pk.h = (_Float16)h0[(size_t)bpw * Nn + ngf];
        __hip_atomic_store((unsigned short*)(hring + hoff), pk.u,
                           __ATOMIC_RELAXED, __HIP_MEMORY_SCOPE_AGENT);
        __syncthreads();
        if (tid == 0)
            __hip_atomic_fetch_add(ctr, 1u, __ATOMIC_RELEASE, __HIP_MEMORY_SCOPE_AGENT);
    }

    int m = wid * 16 + nl16;
    for (int t = 0; t < Ttot; ++t) {
        if (tid == 0) {
            while (__hip_atomic_load(ctr + t, __ATOMIC_RELAXED, __HIP_MEMORY_SCOPE_AGENT)
                   < (uint32_t)NWG_F) {}
            __threadfence();
        }
        __syncthreads();

        const _Float16* hs = hring + (size_t)(t & 1) * HSLOT_ELEMS;
        f32x4 acc = {0.f, 0.f, 0.f, 0.f};
        #pragma unroll
        for (int kb = 0; kb < 24; ++kb) {
            f16x8 a = *(const f16x8*)(hs + ((kb * 4 + q) * 64 + m) * 8);
            acc = __builtin_amdgcn_mfma_f32_16x16x32_f16(a, breg[kb], acc, 0, 0, 0);
        }
        const float* xp = x + ((size_t)m * Ttot + t) * Dd + q * 8;
        #pragma unroll
        for (int kb2 = 0; kb2 < 24; ++kb2) {
            f32x4 x0 = *(const f32x4*)(xp + kb2 * 32);
            f32x4 x1 = *(const f32x4*)(xp + kb2 * 32 + 4);
            f16x8 a;
            a[0]=(_Float16)x0[0]; a[1]=(_Float16)x0[1]; a[2]=(_Float16)x0[2]; a[3]=(_Float16)x0[3];
            a[4]=(_Float16)x1[0]; a[5]=(_Float16)x1[1]; a[6]=(_Float16)x1[2]; a[7]=(_Float16)x1[3];
            acc = __builtin_amdgcn_mfma_f32_16x16x32_f16(a, breg[24 + kb2], acc, 0, 0, 0);
        }
        #pragma unroll
        for (int r = 0; r < 4; ++r)
            gbuf[wid * 16 + q * 4 + r][nl16] = acc[r];
        __syncthreads();
        {
            f32x4 v = *(const f32x4*)&gbuf[bpw][4 * nl];
            float iv = hsig(v[0]), fv = hsig(v[1]);
            float gv = tanhf(v[2]), ov = hsig(v[3]);
            float cn = cst[bpw][nl] * fv + iv * gv;
            cst[bpw][nl] = cn;
            float hv = tanhf(cn) * ov;
            __builtin_nontemporal_store(hv, out + ((size_t)bpw * Ttot + t) * Nn + ngf);
            union { _Float16 h; unsigned short u; } pk;
            pk.h = (_Float16)hv;
            __hip_atomic_store((unsigned short*)(hring + (size_t)((t + 1) & 1) * HSLOT_ELEMS + hoff),
                               pk.u, __ATOMIC_RELAXED, __HIP_MEMORY_SCOPE_AGENT);
        }
        __syncthreads();
        if (tid == 0)
            __hip_atomic_fetch_add(ctr + t + 1, 1u, __ATOMIC_RELEASE, __HIP_MEMORY_SCOPE_AGENT);
    }
}

extern "C" void kernel_launch(void* const* d_in, const int* in_sizes, int n_in,
                              void* d_out, int out_size, void* d_ws, size_t ws_size,
                              hipStream_t stream) {
    const float* xp  = (const float*)d_in[0];
    const float* h0p = (const float*)d_in[1];
    const float* c0p = (const float*)d_in[2];
    const float* wki = (const float*)d_in[3];
    const float* wri = (const float*)d_in[4];
    const float* wkf = (const float*)d_in[5];
    const float* wrf = (const float*)d_in[6];
    const float* wkc = (const float*)d_in[7];
    const float* wrc = (const float*)d_in[8];
    const float* wko = (const float*)d_in[9];
    const float* wro = (const float*)d_in[10];
    float* outp = (float*)d_out;

    uint8_t* ws = (uint8_t*)d_ws;
    uint32_t* ctr   = (uint32_t*)(ws + CTR_OFF);
    _Float16* hring = (_Float16*)(ws + HRING_OFF);
    float*    cstb  = (float*)(ws + CST_OFF);
    _Float16* WBk   = (_Float16*)(ws + WBK_OFF);
    _Float16* WBr   = (_Float16*)(ws + WBR_OFF);
    _Float16* G     = (_Float16*)(ws + G_OFF);

    int Tc = 0;
    const int cands[4] = {1024, 512, 256, 128};
    for (int i = 0; i < 4; ++i) {
        size_t need = (size_t)G_OFF + (size_t)cands[i] * 64 * 3072 * 2;
        if (need <= ws_size) { Tc = cands[i]; break; }
    }

    zero_ctr<<<1, 256, 0, stream>>>(ctr);
    if (Tc) {
        prep_w<<<1152, 256, 0, stream>>>(wki, wri, wkf, wrf, wkc, wrc, wko, wro, WBk, WBr);
        int tpb = Tc / 128;
        for (int t0 = 0; t0 < Ttot; t0 += Tc) {
            gemm_g<<<dim3(64 * tpb, 12), 256, 0, stream>>>(xp, WBk, G, t0, tpb);
            recur_g<<<NWG_G, 256, 0, stream>>>(WBr, G, h0p, c0p, outp, hring, ctr, cstb,
                                               t0, t0 + Tc, t0 == 0 ? 1 : 0);
        }
    } else {
        recur_nog<<<NWG_F, 256, 0, stream>>>(wki, wri, wkf, wrf, wkc, wrc, wko, wro,
                                             xp, h0p, c0p, outp, hring, ctr);
    }
}